// Round 9
// baseline (787.722 us; speedup 1.0000x reference)
//
#include <hip/hip_runtime.h>
#include <stdint.h>
#include <stddef.h>

// CNNLSTM: embed -> conv1d(K=5) -> ReLU -> maxpool4 -> LSTM(T=1023,H=128) -> fc(2)
// Inputs: x int32; all float tensors float32. Output f32.
// R9: LSTM recurrence via MFMA with 8 batches per WG (8 WGs x 512 thr).
//   Per step: gates[512x8] = W[512x128] @ H[128x8] -> 16 MFMA/wave instead of
//   64 dot2/thread (R4-R8 were stuck at ~1400 cy/step, VALU-issue-bound).

typedef __bf16 bf16;
typedef __bf16 bf16x8 __attribute__((ext_vector_type(8)));
typedef float  f32x4  __attribute__((ext_vector_type(4)));
typedef _Float16 f16;
typedef f16 f16x2 __attribute__((ext_vector_type(2)));
typedef f16 f16x8 __attribute__((ext_vector_type(8)));

#define MFMA16(a, b, c)  __builtin_amdgcn_mfma_f32_16x16x32_bf16((a), (b), (c), 0, 0, 0)
#define MFMAH(a, b, c)   __builtin_amdgcn_mfma_f32_16x16x32_f16((a), (b), (c), 0, 0, 0)

// Barrier draining LDS (lgkm) but NOT in-flight global prefetch loads.
#define LGKM_BARRIER() asm volatile("s_waitcnt lgkmcnt(0)\ns_barrier" ::: "memory")

#if __has_builtin(__builtin_amdgcn_exp2f)
#define EXP2F(x) __builtin_amdgcn_exp2f(x)
#else
#define EXP2F(x) __exp2f(x)
#endif

// DPP row_shr:8 (ctrl 0x118): lane l gets lane l-8 within each 16-lane row.
template <int CTRL>
__device__ inline float qdpp(float v) {
    int s = __builtin_bit_cast(int, v);
    int d = __builtin_amdgcn_update_dpp(0, s, CTRL, 0xF, 0xF, true);
    return __builtin_bit_cast(float, d);
}
#define QSHR8(v) qdpp<0x118>(v)

// Clamp-free activations (exp2 overflow/underflow give exact limits, no NaN).
__device__ inline float sigm_(float v) {
    return __builtin_amdgcn_rcpf(1.f + EXP2F(-1.44269504f * v));
}
__device__ inline float tanh_(float v) {
    return 1.f - 2.f * __builtin_amdgcn_rcpf(1.f + EXP2F(2.88539008f * v));
}

// ---------------- ws layout (bytes) ----------------
#define WS_BT     0               // conv weights repacked [64][640] bf16 =    81,920
#define WS_WIHB   81920           // w_ih bf16 [512][64]                  =    65,536
#define WS_POOLED 278528          // pooled bf16 [64][1024][64]           = 8,388,608
#define WS_EMB    8667136         // emb bf16 [20000][128]                = 5,120,000
#define WS_XG     8667136         // xg f16, 8 bg x 1024 t x 4096 vals    = 67,108,864
// xg layout: idx = ((bg*1024 + t)*4096) + (((w*4 + quad)*8 + n8)*16) + rp*8 + g*2 + rs
// (per LSTM thread: one contiguous 16B f16x8 per step)

// ============ prep A: emb f32 -> bf16 ============
__global__ void emb_cvt_k(const float* __restrict__ emb, bf16* __restrict__ embb) {
    int g = blockIdx.x * 256 + threadIdx.x;
    f32x4 v = *(const f32x4*)(emb + g * 4);
    bf16* d = embb + g * 4;
    d[0] = (bf16)v[0]; d[1] = (bf16)v[1]; d[2] = (bf16)v[2]; d[3] = (bf16)v[3];
}

// ============ prep B: conv_w repack->bf16; w_ih->bf16 ============
__global__ void prep_small_k(const float* __restrict__ conv_w, bf16* __restrict__ bt,
                             const float* __restrict__ w_ih, bf16* __restrict__ w_ihb) {
    int g = blockIdx.x * 256 + threadIdx.x;
    if (g < 64 * 640) {
        int f = g / 640, kk = g - f * 640;
        int k = kk >> 7, e = kk & 127;
        bt[g] = (bf16)conv_w[(f * 128 + e) * 5 + k];
    } else {
        int h = g - 64 * 640;
        if (h < 512 * 64) w_ihb[h] = (bf16)w_ih[h];
    }
}

// ============ kernel 1: embed-gather + conv + ReLU + pool4 ============
__global__ __launch_bounds__(256, 2) void conv_pool_k(
    const int* __restrict__ x, const bf16* __restrict__ embb,
    const bf16* __restrict__ bt, const float* __restrict__ conv_b,
    bf16* __restrict__ pooled)
{
    __shared__ bf16 T[144 * 136];
    const int b   = blockIdx.x >> 5;
    const int l0  = (blockIdx.x & 31) << 7;
    const int tid = threadIdx.x;
    const int ln  = tid & 63, w = tid >> 6;
    const int l15 = ln & 15, quad = ln >> 4;
    const int f   = w * 16 + l15;

    bf16x8 bfrag[20];
    #pragma unroll
    for (int kc = 0; kc < 20; ++kc) {
        uint4 v = *(const uint4*)(bt + f * 640 + kc * 32 + quad * 8);
        bfrag[kc] = __builtin_bit_cast(bf16x8, v);
    }
    const float cb = conv_b[f];

    #pragma unroll
    for (int p = 0; p < 9; ++p) {
        int r = p * 16 + (tid >> 4);
        int cg = tid & 15;
        int token = l0 + r; if (token > 4095) token = 4095;
        int idx = x[b * 4096 + token];
        uint4 v = *(const uint4*)(embb + idx * 128 + cg * 8);
        *(uint4*)(&T[r * 136 + cg * 8]) = v;
    }
    __syncthreads();

    f32x4 acc[8];
    #pragma unroll
    for (int tm = 0; tm < 8; ++tm) acc[tm] = (f32x4){0.f, 0.f, 0.f, 0.f};

    #pragma unroll
    for (int kc = 0; kc < 20; ++kc) {
        const int ktap = kc >> 2;
        const int ecol = (kc & 3) * 32 + quad * 8;
        #pragma unroll
        for (int tm = 0; tm < 8; ++tm) {
            int row = tm * 16 + l15 + ktap;
            bf16x8 a = *(const bf16x8*)(&T[row * 136 + ecol]);
            acc[tm] = MFMA16(a, bfrag[kc], acc[tm]);
        }
    }

    #pragma unroll
    for (int tm = 0; tm < 8; ++tm) {
        float mx = fmaxf(fmaxf(acc[tm][0], acc[tm][1]), fmaxf(acc[tm][2], acc[tm][3]));
        mx = fmaxf(mx + cb, 0.f);
        int t = (l0 >> 2) + tm * 4 + quad;
        if (t < 1023) pooled[(b * 1024 + t) * 64 + f] = (bf16)mx;
    }
}

// ============ kernel 2: xg = w_ih @ pooled^T + bias (transposed GEMM) ============
// D[m=gate-row][n=time]. 256 WGs (b x 4 time-segs) x 256 thr (4 waves).
// Wave w owns units 32w..32w+31 for all 4 gates (8 m-tiles). C-frag rows =
// 4 consecutive gate rows (same gate, units u0..u0+3) -> f16x2 stores into
// the LSTM's per-thread x layout.
__global__ __launch_bounds__(256, 2) void xg_gemm_k(
    const bf16* __restrict__ pooled, const bf16* __restrict__ w_ihb,
    const float* __restrict__ b_ih, const float* __restrict__ b_hh,
    f16* __restrict__ xg)
{
    const int blk = blockIdx.x;
    const int b   = blk >> 2;         // batch 0..63
    const int tsg = blk & 3;          // time segment (256 each)
    const int tid = threadIdx.x;
    const int l   = tid & 63, w = tid >> 6;
    const int quad = l >> 4, n16 = l & 15;
    const int bg = b >> 3, n8 = b & 7;

    // A-frags: [gate g][ti 0..1][k-chunk c 0..1]; rows nn = 128g + 32w + 16ti + n16
    bf16x8 A[4][2][2];
    float bias[4][2][4];
    #pragma unroll
    for (int g = 0; g < 4; ++g)
        #pragma unroll
        for (int ti = 0; ti < 2; ++ti) {
            int nn = 128 * g + 32 * w + 16 * ti + n16;
            #pragma unroll
            for (int c = 0; c < 2; ++c) {
                uint4 v = *(const uint4*)(w_ihb + nn * 64 + c * 32 + quad * 8);
                A[g][ti][c] = __builtin_bit_cast(bf16x8, v);
            }
            #pragma unroll
            for (int r = 0; r < 4; ++r) {
                int nr = 128 * g + 32 * w + 16 * ti + quad * 4 + r;
                bias[g][ti][r] = b_ih[nr] + b_hh[nr];
            }
        }

    const f32x4 zero4 = (f32x4){0.f, 0.f, 0.f, 0.f};
    for (int nt = 0; nt < 16; ++nt) {
        const int t = tsg * 256 + nt * 16 + n16;   // this lane's time col
        uint4 v0 = *(const uint4*)(pooled + (b * 1024 + t) * 64 + quad * 8);
        uint4 v1 = *(const uint4*)(pooled + (b * 1024 + t) * 64 + 32 + quad * 8);
        bf16x8 B0 = __builtin_bit_cast(bf16x8, v0);
        bf16x8 B1 = __builtin_bit_cast(bf16x8, v1);
        #pragma unroll
        for (int g = 0; g < 4; ++g)
            #pragma unroll
            for (int ti = 0; ti < 2; ++ti) {
                f32x4 acc = MFMA16(A[g][ti][0], B0, zero4);
                acc = MFMA16(A[g][ti][1], B1, acc);
                int w_c = 2 * w + ti;
                size_t base = ((size_t)(bg * 1024 + t)) * 4096
                            + (((w_c * 4 + quad) * 8 + n8) * 16);
                f16x2 s0 = {(f16)(acc[0] + bias[g][ti][0]), (f16)(acc[1] + bias[g][ti][1])};
                f16x2 s1 = {(f16)(acc[2] + bias[g][ti][2]), (f16)(acc[3] + bias[g][ti][3])};
                *(f16x2*)(xg + base + g * 2) = s0;
                *(f16x2*)(xg + base + 8 + g * 2) = s1;
            }
    }
}

// ============ kernel 3: LSTM recurrence (MFMA, 8 batches/WG) + fc head ============
// 8 WGs x 512 threads (8 waves). Wave w: A-frags = W rows {128g+16w+n16},
// 4 gates x 4 k-chunks (64 VGPRs, f16). H in LDS [n][k] f16, row stride 144
// (conflict-free b128). Thread (w,quad,n16): C cols = n16; DPP row_shr:8
// moves acc regs 2,3 to lanes n16>=8 so every lane activates 2 units
// (unit u0+rp*2+rs, batch n8) -- dense transcendentals, local cell state.
__global__ __launch_bounds__(512, 2) void lstm_fc_k(
    const f16* __restrict__ xg, const float* __restrict__ w_hh,
    const float* __restrict__ fc_w, const float* __restrict__ fc_b,
    float* __restrict__ out)
{
    __shared__ __align__(16) f16 Hb[2][16 * 144];
    const int bg  = blockIdx.x;       // batch group (8 batches)
    const int tid = threadIdx.x;
    const int l   = tid & 63, w = tid >> 6;
    const int quad = l >> 4, n16 = l & 15;
    const int n8 = n16 & 7, rp = n16 >> 3;
    const int u0 = 16 * w + quad * 4;

    // A-frags from w_hh f32 -> f16: wf[gate][k-chunk]
    f16x8 wf[4][4];
    #pragma unroll
    for (int g = 0; g < 4; ++g) {
        const float* wr = w_hh + (128 * g + 16 * w + n16) * 128;
        #pragma unroll
        for (int c = 0; c < 4; ++c) {
            f32x4 va = *(const f32x4*)(wr + c * 32 + quad * 8);
            f32x4 vb = *(const f32x4*)(wr + c * 32 + quad * 8 + 4);
            wf[g][c] = (f16x8){(f16)va[0], (f16)va[1], (f16)va[2], (f16)va[3],
                               (f16)vb[0], (f16)vb[1], (f16)vb[2], (f16)vb[3]};
        }
    }

    // zero both H buffers (rows 8..15 stay 0 forever -> D cols 8..15 = 0)
    for (int i = tid; i < 2 * 16 * 144 / 2; i += 512) ((uint32_t*)Hb)[i] = 0;

    const f16* xp = xg + (size_t)bg * 1024 * 4096
                  + (((w * 4 + quad) * 8 + n8) * 16) + rp * 8;
    f16x8 xs0 = *(const f16x8*)(xp);
    f16x8 xs1 = *(const f16x8*)(xp + 4096);

    float cst0 = 0.f, cst1 = 0.f;
    int p = 0;
    const f32x4 zero4 = (f32x4){0.f, 0.f, 0.f, 0.f};
    LGKM_BARRIER();

    auto step = [&](f16x8 xc) {
        const f16* hrow = &Hb[p][n16 * 144 + quad * 8];
        f16x8 b0 = *(const f16x8*)(hrow);
        f16x8 b1 = *(const f16x8*)(hrow + 32);
        f16x8 b2 = *(const f16x8*)(hrow + 64);
        f16x8 b3 = *(const f16x8*)(hrow + 96);
        f32x4 ai = MFMAH(wf[0][0], b0, zero4);
        f32x4 af = MFMAH(wf[1][0], b0, zero4);
        f32x4 ag = MFMAH(wf[2][0], b0, zero4);
        f32x4 ao = MFMAH(wf[3][0], b0, zero4);
        ai = MFMAH(wf[0][1], b1, ai); af = MFMAH(wf[1][1], b1, af);
        ag = MFMAH(wf[2][1], b1, ag); ao = MFMAH(wf[3][1], b1, ao);
        ai = MFMAH(wf[0][2], b2, ai); af = MFMAH(wf[1][2], b2, af);
        ag = MFMAH(wf[2][2], b2, ag); ao = MFMAH(wf[3][2], b2, ao);
        ai = MFMAH(wf[0][3], b3, ai); af = MFMAH(wf[1][3], b3, af);
        ag = MFMAH(wf[2][3], b3, ag); ao = MFMAH(wf[3][3], b3, ao);

        // redistribute regs 2,3 to lanes n16>=8 (their own cols are zero)
        float i2 = QSHR8(ai[2]), i3 = QSHR8(ai[3]);
        float f2 = QSHR8(af[2]), f3 = QSHR8(af[3]);
        float g2 = QSHR8(ag[2]), g3 = QSHR8(ag[3]);
        float o2 = QSHR8(ao[2]), o3 = QSHR8(ao[3]);
        float si0 = rp ? i2 : ai[0], si1 = rp ? i3 : ai[1];
        float sf0 = rp ? f2 : af[0], sf1 = rp ? f3 : af[1];
        float sg0 = rp ? g2 : ag[0], sg1 = rp ? g3 : ag[1];
        float so0 = rp ? o2 : ao[0], so1 = rp ? o3 : ao[1];

        float iv0 = sigm_(si0 + (float)xc[0]), iv1 = sigm_(si1 + (float)xc[1]);
        float fv0 = sigm_(sf0 + (float)xc[2]), fv1 = sigm_(sf1 + (float)xc[3]);
        float gv0 = tanh_(sg0 + (float)xc[4]), gv1 = tanh_(sg1 + (float)xc[5]);
        float ov0 = sigm_(so0 + (float)xc[6]), ov1 = sigm_(so1 + (float)xc[7]);
        cst0 = fv0 * cst0 + iv0 * gv0;
        cst1 = fv1 * cst1 + iv1 * gv1;
        f16x2 hv = {(f16)(ov0 * tanh_(cst0)), (f16)(ov1 * tanh_(cst1))};
        *(f16x2*)(&Hb[p ^ 1][n8 * 144 + u0 + rp * 2]) = hv;
        p ^= 1;
        LGKM_BARRIER();
    };

    for (int s = 0; s < 1022; s += 2) {
        f16x8 c0 = xs0;
        xs0 = *(const f16x8*)(xp + (size_t)(s + 2) * 4096);  // prefetch s+2
        step(c0);
        f16x8 c1 = xs1;
        xs1 = *(const f16x8*)(xp + (size_t)(s + 3) * 4096);  // prefetch s+3 (<=1023)
        step(c1);
    }
    step(xs0);   // s = 1022

    // fc: out[bg*8+bb][c] = h . fc_w[c] + fc_b[c]; final h in Hb[p]
    if (tid < 128) {
        int bb = tid >> 4, idx = tid & 15;
        float p0 = 0.f, p1 = 0.f;
        #pragma unroll
        for (int j = 0; j < 8; ++j) {
            float hv = (float)Hb[p][bb * 144 + idx * 8 + j];
            p0 += hv * fc_w[idx * 8 + j];
            p1 += hv * fc_w[128 + idx * 8 + j];
        }
        #pragma unroll
        for (int off = 8; off > 0; off >>= 1) {
            p0 += __shfl_down(p0, off, 16);
            p1 += __shfl_down(p1, off, 16);
        }
        if (idx == 0) {
            out[(bg * 8 + bb) * 2 + 0] = p0 + fc_b[0];
            out[(bg * 8 + bb) * 2 + 1] = p1 + fc_b[1];
        }
    }
}

// ============================ launcher ============================
extern "C" void kernel_launch(void* const* d_in, const int* in_sizes, int n_in,
                              void* d_out, int out_size, void* d_ws, size_t ws_size,
                              hipStream_t stream) {
    const int*   x      = (const int*)d_in[0];
    const float* emb    = (const float*)d_in[1];
    const float* conv_w = (const float*)d_in[2];
    const float* conv_b = (const float*)d_in[3];
    const float* w_ih   = (const float*)d_in[4];
    const float* w_hh   = (const float*)d_in[5];
    const float* b_ih   = (const float*)d_in[6];
    const float* b_hh   = (const float*)d_in[7];
    const float* fc_w   = (const float*)d_in[8];
    const float* fc_b   = (const float*)d_in[9];
    float* out = (float*)d_out;

    char* ws = (char*)d_ws;
    bf16* bt     = (bf16*)(ws + WS_BT);
    bf16* w_ihb  = (bf16*)(ws + WS_WIHB);
    bf16* pooled = (bf16*)(ws + WS_POOLED);
    bf16* embb   = (bf16*)(ws + WS_EMB);
    f16*  xg     = (f16*)(ws + WS_XG);   // overlaps embb (emb dead after conv_pool)

    emb_cvt_k<<<2500, 256, 0, stream>>>(emb, embb);
    prep_small_k<<<288, 256, 0, stream>>>(conv_w, bt, w_ih, w_ihb);
    conv_pool_k<<<2048, 256, 0, stream>>>(x, embb, bt, conv_b, pooled);
    xg_gemm_k<<<256, 256, 0, stream>>>(pooled, w_ihb, b_ih, b_hh, xg);
    lstm_fc_k<<<8, 512, 0, stream>>>(xg, w_hh, fc_w, fc_b, out);
}